// Round 10
// baseline (1266.666 us; speedup 1.0000x reference)
//
#include <hip/hip_runtime.h>
#include <stdint.h>

typedef unsigned long long u64;

#define PADW 134
#define WPR 3                        // 3 u64 words per 134-voxel row
#define ROWS_PER_B (PADW * PADW)     // 17,956 rows per batch
#define WPB (ROWS_PER_B * WPR)       // 53,868 words per batch
#define NBATCH 2
#define NROWS (NBATCH * ROWS_PER_B)  // 35,912
#define NWORDS (NBATCH * WPB)        // 107,736
#define NV 128
#define NV3 (NV * NV * NV)
#define PAD 3
#define GRID 424                     // <= 512 = 256 CUs * 2 blocks/CU (launch_bounds)
#define THREADS 256

// Bit i of word j in row (z,y) = voxel x = j*64+i. Invariant: all STORED buffers
// (X, E*, sk*) have invalid bits (word 2 bits 6..63) == 0.

__device__ __forceinline__ bool inR(int v) { return (unsigned)v < (unsigned)PADW; }

__device__ __forceinline__ void load3w(const u64* __restrict__ B, int z, int y, int j,
                                       u64 w[3]) {
  const u64* p = B + (z * PADW + y) * WPR;
  w[0] = j > 0 ? p[j - 1] : 0ULL;
  w[1] = p[j];
  w[2] = j < 2 ? p[j + 1] : 0ULL;
}

__device__ __forceinline__ u64 hdilw(const u64 w[3]) {
  return w[1] | (w[1] << 1) | (w[0] >> 63) | (w[1] >> 1) | (w[2] << 63);
}

__device__ __forceinline__ u64 herow(const u64 w[3], int j) {
  u64 lin = (j == 0) ? 1ULL : (w[0] >> 63);
  u64 rin = (j == 2) ? (1ULL << 5) : (w[2] << 63);
  return w[1] & ((w[1] << 1) | lin) & ((w[1] >> 1) | rin);
}

__device__ __forceinline__ void decompW(int idx, int& b, int& z, int& y, int& j) {
  b = idx / WPB;
  int r = idx - b * WPB;
  z = r / (PADW * WPR);
  int r2 = r - z * (PADW * WPR);
  y = r2 / WPR;
  j = r2 - y * WPR;
}

// ---------------------------------------------------------------- grid barrier
struct __align__(64) BarSlot { unsigned v; unsigned pad[15]; };

__device__ __forceinline__ void gbar(BarSlot* cnt, unsigned* rel, unsigned k) {
  __syncthreads();
  if (threadIdx.x == 0) {
    __threadfence();  // publish this block's phase writes (agent scope)
    __hip_atomic_fetch_add(&cnt[blockIdx.x & 7].v, 1u, __ATOMIC_ACQ_REL,
                           __HIP_MEMORY_SCOPE_AGENT);
    if (blockIdx.x == 0) {
      for (;;) {
        unsigned s = 0;
#pragma unroll
        for (int i = 0; i < 8; ++i)
          s += __hip_atomic_load(&cnt[i].v, __ATOMIC_ACQUIRE, __HIP_MEMORY_SCOPE_AGENT);
        if (s >= k * (unsigned)GRID) break;
        __builtin_amdgcn_s_sleep(8);
      }
      __hip_atomic_store(rel, k, __ATOMIC_RELEASE, __HIP_MEMORY_SCOPE_AGENT);
    } else {
      while (__hip_atomic_load(rel, __ATOMIC_ACQUIRE, __HIP_MEMORY_SCOPE_AGENT) < k)
        __builtin_amdgcn_s_sleep(8);
    }
    __threadfence();  // acquire side: invalidate stale cached data
  }
  __syncthreads();
}

// ---------------------------------------------------------------- phase bodies
__device__ __forceinline__ void binpack_dev(const float* __restrict__ logit,
                                            u64* __restrict__ X) {
  int w = blockIdx.x * 4 + (threadIdx.x >> 6);  // global wave id, 4 waves/block
  int lane = threadIdx.x & 63;
  const float TH = 0.84729786f;  // ln(0.7/0.3): sigmoid(l)>0.7 <=> l>TH
  for (int rid = w; rid < NROWS; rid += GRID * 4) {
    int b = rid / ROWS_PER_B;
    int r = rid - b * ROWS_PER_B;
    int z = r / PADW;
    int y = r - z * PADW;
    bool padrow = (z < PAD || z >= PAD + NV || y < PAD || y >= PAD + NV);
    u64* rowp = X + (size_t)b * WPB + (z * PADW + y) * WPR;
#pragma unroll
    for (int j = 0; j < WPR; ++j) {
      int x = j * 64 + lane;
      bool pred = false;
      if (x < PADW) {
        if (padrow || x < PAD || x >= PAD + NV) {
          pred = true;  // pad voxel = 1
        } else {
          float l = logit[(((size_t)b * NV + (z - PAD)) * NV + (y - PAD)) * NV + (x - PAD)];
          pred = l > TH;
        }
      }
      u64 wv = __ballot(pred);
      if (lane == 0) rowp[j] = wv;
    }
  }
}

__device__ __forceinline__ void ero_dev(const u64* __restrict__ in, u64* __restrict__ out) {
  int idx = blockIdx.x * THREADS + threadIdx.x;
  if (idx >= NWORDS) return;
  int b, z, y, j;
  decompW(idx, b, z, y, j);
  const u64* Bb = in + (size_t)b * WPB;
  u64 c3[3];
  load3w(Bb, z, y, j, c3);
  u64 e = herow(c3, j);
  if (inR(y - 1)) e &= Bb[(z * PADW + y - 1) * WPR + j];
  if (inR(y + 1)) e &= Bb[(z * PADW + y + 1) * WPR + j];
  if (inR(z - 1)) e &= Bb[((z - 1) * PADW + y) * WPR + j];
  if (inR(z + 1)) e &= Bb[((z + 1) * PADW + y) * WPR + j];
  out[idx] = e;
}

// sk = X & ~dil26(E1);  E2 = ero6(E1)
__device__ __forceinline__ void init_dev(const u64* __restrict__ X, const u64* __restrict__ E1,
                                         u64* __restrict__ sk, u64* __restrict__ E2) {
  int idx = blockIdx.x * THREADS + threadIdx.x;
  if (idx >= NWORDS) return;
  int b, z, y, j;
  decompW(idx, b, z, y, j);
  size_t boff = (size_t)b * WPB;
  const u64* Eb = E1 + boff;
  u64 acc = 0;
  u64 cc3[3];
  u64 ecross = ~0ULL;
#pragma unroll
  for (int dz = -1; dz <= 1; ++dz) {
#pragma unroll
    for (int dy = -1; dy <= 1; ++dy) {
      int zz = z + dz, yy = y + dy;
      if (!inR(zz) || !inR(yy)) continue;  // dil OR-identity / ero AND-identity
      u64 t3[3];
      load3w(Eb, zz, yy, j, t3);
      acc |= hdilw(t3);
      if (dz == 0 && dy == 0) { cc3[0] = t3[0]; cc3[1] = t3[1]; cc3[2] = t3[2]; }
      else if (dz * dz + dy * dy == 1) ecross &= t3[1];
    }
  }
  u64 e = herow(cc3, j) & ecross;
  sk[idx] = X[idx] & ~acc;  // acc junk bits killed by clean X
  E2[idx] = e;
}

// delta = E1 & ~dil26(E2); sk2 = delta | sk | (X & dil26(sk)); E3 = ero6(E2)
__device__ __forceinline__ void upd_dev(const u64* __restrict__ X, const u64* __restrict__ E1,
                                        const u64* __restrict__ E2, const u64* __restrict__ sk,
                                        u64* __restrict__ sk2, u64* __restrict__ E3) {
  int idx = blockIdx.x * THREADS + threadIdx.x;
  if (idx >= NWORDS) return;
  int b, z, y, j;
  decompW(idx, b, z, y, j);
  size_t boff = (size_t)b * WPB;
  const u64* Eb = E2 + boff;
  const u64* Sb = sk + boff;
  u64 acc = 0, dsk = 0;
  u64 cc3[3], skcw = 0;
  u64 ecross = ~0ULL;
#pragma unroll
  for (int dz = -1; dz <= 1; ++dz) {
#pragma unroll
    for (int dy = -1; dy <= 1; ++dy) {
      int zz = z + dz, yy = y + dy;
      if (!inR(zz) || !inR(yy)) continue;
      u64 t3[3], s3[3];
      load3w(Eb, zz, yy, j, t3);
      load3w(Sb, zz, yy, j, s3);
      acc |= hdilw(t3);
      dsk |= hdilw(s3);
      if (dz == 0 && dy == 0) {
        cc3[0] = t3[0]; cc3[1] = t3[1]; cc3[2] = t3[2];
        skcw = s3[1];
      } else if (dz * dz + dy * dy == 1) {
        ecross &= t3[1];
      }
    }
  }
  u64 e = herow(cc3, j) & ecross;
  u64 delta = E1[idx] & ~acc;
  u64 s1 = (X[idx] & dsk) | skcw;
  sk2[idx] = delta | s1;
  E3[idx] = e;
}

__device__ __forceinline__ void reduce_dev(const float* __restrict__ logit,
                                           const float* __restrict__ vcl,
                                           const u64* __restrict__ S,
                                           double* __restrict__ partials) {
  int tid = blockIdx.x * THREADS + threadIdx.x;
  float p[8];
#pragma unroll
  for (int k = 0; k < 8; ++k) p[k] = 0.f;
  for (int s = tid; s < NV3 / 4; s += GRID * THREADS) {
    int i = s << 2;
    int z = i >> 14, y = (i >> 7) & 127, x = i & 127;
#pragma unroll
    for (int b = 0; b < NBATCH; ++b) {
      float4 lv = ((const float4*)(logit + (size_t)b * NV3))[s];
      float4 cv = ((const float4*)(vcl + (size_t)b * NV3))[s];
      const u64* rowp = S + (size_t)b * WPB + ((size_t)(z + PAD) * PADW + (y + PAD)) * WPR;
      float lf[4] = {lv.x, lv.y, lv.z, lv.w};
      float cf[4] = {cv.x, cv.y, cv.z, cv.w};
#pragma unroll
      for (int k = 0; k < 4; ++k) {
        float vp = 1.0f / (1.0f + expf(-lf[k]));
        int xp = x + k + PAD;
        u64 w = rowp[xp >> 6];
        float sv = (float)((w >> (xp & 63)) & 1ULL);
        float c = cf[k];
        p[b * 4 + 0] += vp * c;
        p[b * 4 + 1] += c;
        p[b * 4 + 2] += c * vp * sv;
        p[b * 4 + 3] += vp * sv;
      }
    }
  }
#pragma unroll
  for (int k = 0; k < 8; ++k)
    for (int off = 32; off > 0; off >>= 1) p[k] += __shfl_down(p[k], off);
  __shared__ float ls[4][8];
  int wid = threadIdx.x >> 6, lane = threadIdx.x & 63;
  if (lane == 0) {
#pragma unroll
    for (int k = 0; k < 8; ++k) ls[wid][k] = p[k];
  }
  __syncthreads();
  if (threadIdx.x == 0) {
#pragma unroll
    for (int k = 0; k < 8; ++k)
      partials[k * GRID + blockIdx.x] =
          (double)ls[0][k] + ls[1][k] + ls[2][k] + ls[3][k];
  }
}

__device__ __forceinline__ void finalize_dev(const double* __restrict__ partials,
                                             float* __restrict__ out) {
  int t = threadIdx.x;  // 256 threads, block 0 only
  double s[8];
#pragma unroll
  for (int k = 0; k < 8; ++k) {
    double v = partials[k * GRID + t];
    if (t + 256 < GRID) v += partials[k * GRID + t + 256];
    s[k] = v;
  }
#pragma unroll
  for (int k = 0; k < 8; ++k)
    for (int off = 32; off > 0; off >>= 1) s[k] += __shfl_down(s[k], off);
  __shared__ double ls[8][4];
  int wid = t >> 6, lane = t & 63;
  if (lane == 0) {
#pragma unroll
    for (int k = 0; k < 8; ++k) ls[k][wid] = s[k];
  }
  __syncthreads();
  if (t == 0) {
    double a[8];
#pragma unroll
    for (int k = 0; k < 8; ++k) a[k] = ls[k][0] + ls[k][1] + ls[k][2] + ls[k][3];
    const double eps = 1e-12;
    double tp = 0.5 * ((a[0] + eps) / (a[1] + eps) + (a[4] + eps) / (a[5] + eps));
    double ts = 0.5 * ((a[2] + eps) / (a[3] + eps) + (a[6] + eps) / (a[7] + eps));
    out[0] = (float)(1.0 - (2.0 * tp * ts + eps) / (tp + ts + eps));
  }
}

// ---------------------------------------------------------------- fused kernel
__global__ __launch_bounds__(THREADS, 2) void fused_k(const float* __restrict__ logit,
                                                      const float* __restrict__ vcl,
                                                      u64* __restrict__ ws,
                                                      double* __restrict__ partials,
                                                      BarSlot* cnt, unsigned* rel,
                                                      float* __restrict__ out) {
  u64* B[7];
#pragma unroll
  for (int i = 0; i < 7; ++i) B[i] = ws + (size_t)i * NWORDS;
  unsigned bar = 0;

  binpack_dev(logit, B[0]);                       // p0
  gbar(cnt, rel, ++bar);

  // ---- skeletonize #1 (5 iters)
  u64 *X = B[0], *E1 = B[1], *E2 = B[2], *E3 = B[3], *sk = B[4], *sk2 = B[5];
  ero_dev(X, E1);                                 // p1
  gbar(cnt, rel, ++bar);
  init_dev(X, E1, sk, E2);                        // p2
  gbar(cnt, rel, ++bar);
  for (int it = 0; it < 5; ++it) {                // p3..p7
    upd_dev(X, E1, E2, sk, sk2, E3);
    u64* t = X; X = E1; E1 = E2; E2 = E3; E3 = t;
    t = sk; sk = sk2; sk2 = t;
    gbar(cnt, rel, ++bar);
  }
  u64* S1 = sk;  // binary support == clamped skel

  // ---- skeletonize #2 (2 iters)
  u64 *X2 = S1, *E1b = B[6], *E2b = X, *E3b = E1, *skb = E2, *sk2b = E3;
  ero_dev(X2, E1b);                               // p8
  gbar(cnt, rel, ++bar);
  init_dev(X2, E1b, skb, E2b);                    // p9
  gbar(cnt, rel, ++bar);
  for (int it = 0; it < 2; ++it) {                // p10,p11
    upd_dev(X2, E1b, E2b, skb, sk2b, E3b);
    u64* t = X2; X2 = E1b; E1b = E2b; E2b = E3b; E3b = t;
    t = skb; skb = sk2b; sk2b = t;
    gbar(cnt, rel, ++bar);
  }
  u64* Sfinal = skb;

  reduce_dev(logit, vcl, Sfinal, partials);       // p12
  gbar(cnt, rel, ++bar);                          // bar 13

  if (blockIdx.x == 0) finalize_dev(partials, out);
}

// ---------------------------------------------------------------- host side
extern "C" void kernel_launch(void* const* d_in, const int* in_sizes, int n_in,
                              void* d_out, int out_size, void* d_ws, size_t ws_size,
                              hipStream_t stream) {
  const float* logit = (const float*)d_in[0];  // Vlogit
  const float* vcl = (const float*)d_in[1];    // Vcl
  // d_in[2] (Vedt) unused by the reference loss
  float* out = (float*)d_out;

  u64* ws = (u64*)d_ws;
  size_t bufBytes = (size_t)7 * NWORDS * sizeof(u64);          // 6,033,216
  double* partials = (double*)((char*)d_ws + bufBytes);        // 8*GRID doubles
  size_t parBytes = (size_t)8 * GRID * sizeof(double);         // 27,136
  char* barBase = (char*)d_ws + bufBytes + parBytes;           // 64-aligned
  BarSlot* cnt = (BarSlot*)barBase;                            // 8 * 64 B
  unsigned* rel = (unsigned*)(barBase + 8 * sizeof(BarSlot));

  hipMemsetAsync(barBase, 0, 8 * sizeof(BarSlot) + 64, stream);
  fused_k<<<GRID, THREADS, 0, stream>>>(logit, vcl, ws, partials, cnt, rel, out);
}

// Round 11
// 179.290 us; speedup vs baseline: 7.0649x; 7.0649x over previous
//
#include <hip/hip_runtime.h>
#include <stdint.h>

typedef unsigned long long u64;

#define PADW 134
#define WPR 3                        // 3 u64 words per 134-voxel row
#define ROWS_PER_B (PADW * PADW)     // 17,956 rows per batch
#define WPB (ROWS_PER_B * WPR)       // 53,868 words per batch
#define NBATCH 2
#define NROWS (NBATCH * ROWS_PER_B)  // 35,912
#define NWORDS (NBATCH * WPB)        // 107,736
#define NV 128
#define NV3 (NV * NV * NV)
#define PAD 3
#define RBLK 512                     // stage-1 reduction blocks

// Bit i of word j in row (z,y) = voxel x = j*64+i. Invariant: all STORED buffers
// (X, E*, sk*) have invalid bits (word 2 bits 6..63) == 0.

__device__ __forceinline__ bool inR(int v) { return (unsigned)v < (unsigned)PADW; }

__device__ __forceinline__ void loadRow(const u64* __restrict__ B, int z, int y, u64 r[3]) {
  const u64* p = B + (z * PADW + y) * WPR;
  r[0] = p[0]; r[1] = p[1]; r[2] = p[2];
}

// load word j-1, j, j+1 of row (z,y); missing edge words -> 0
__device__ __forceinline__ void load3w(const u64* __restrict__ B, int z, int y, int j,
                                       u64 w[3]) {
  const u64* p = B + (z * PADW + y) * WPR;
  w[0] = j > 0 ? p[j - 1] : 0ULL;
  w[1] = p[j];
  w[2] = j < 2 ? p[j + 1] : 0ULL;
}

// horizontal 3-dilation of word j given its (j-1,j,j+1) triple (OOB x -> 0)
__device__ __forceinline__ u64 hdilw(const u64 w[3]) {
  return w[1] | (w[1] << 1) | (w[0] >> 63) | (w[1] >> 1) | (w[2] << 63);
}

// horizontal 3-erosion of word j given triple (OOB x -> 1 edge rules)
__device__ __forceinline__ u64 herow(const u64 w[3], int j) {
  u64 lin = (j == 0) ? 1ULL : (w[0] >> 63);
  u64 rin = (j == 2) ? (1ULL << 5) : (w[2] << 63);
  return w[1] & ((w[1] << 1) | lin) & ((w[1] >> 1) | rin);
}

// full-row horizontal 3-erosion (compile-time indexed)
__device__ __forceinline__ void eroX(const u64 c[3], u64 e[3]) {
  e[0] = c[0] & ((c[0] << 1) | 1ULL)         & ((c[0] >> 1) | (c[1] << 63));
  e[1] = c[1] & ((c[1] << 1) | (c[0] >> 63)) & ((c[1] >> 1) | (c[2] << 63));
  e[2] = c[2] & ((c[2] << 1) | (c[1] >> 63)) & ((c[2] >> 1) | (1ULL << 5));
}

__device__ __forceinline__ u64 selj(u64 r0, u64 r1, u64 r2, int j) {
  return (j == 0) ? r0 : ((j == 1) ? r1 : r2);
}

// horizontal dilation of word j from a FULL clean row (r0,r1,r2)
__device__ __forceinline__ u64 hdilj(u64 r0, u64 r1, u64 r2, int j) {
  u64 a  = selj(r0, r1, r2, j);
  u64 am = (j == 0) ? 0ULL : ((j == 1) ? r0 : r1);
  u64 ap = (j == 2) ? 0ULL : ((j == 0) ? r1 : r2);
  return a | (a << 1) | (am >> 63) | (a >> 1) | (ap << 63);
}

__device__ __forceinline__ void decompW(int idx, int& b, int& z, int& y, int& j) {
  b = idx / WPB;
  int r = idx - b * WPB;
  z = r / (PADW * WPR);
  int r2 = r - z * (PADW * WPR);
  y = r2 / WPR;
  j = r2 - y * WPR;
}

// ero6 of a full row: e[0..2] (clean)
__device__ __forceinline__ void eroRowFull(const u64* __restrict__ Bb, int z, int y,
                                           u64 e[3]) {
  u64 c[3], n[3];
  loadRow(Bb, z, y, c);
  eroX(c, e);
  if (inR(y - 1)) { loadRow(Bb, z, y - 1, n); e[0] &= n[0]; e[1] &= n[1]; e[2] &= n[2]; }
  if (inR(y + 1)) { loadRow(Bb, z, y + 1, n); e[0] &= n[0]; e[1] &= n[1]; e[2] &= n[2]; }
  if (inR(z - 1)) { loadRow(Bb, z - 1, y, n); e[0] &= n[0]; e[1] &= n[1]; e[2] &= n[2]; }
  if (inR(z + 1)) { loadRow(Bb, z + 1, y, n); e[0] &= n[0]; e[1] &= n[1]; e[2] &= n[2]; }
}

// ---------------------------------------------------------------- binarize + pad + pack
__global__ void binpack_k(const float* __restrict__ logit, u64* __restrict__ X) {
  int wid = (blockIdx.x * blockDim.x + threadIdx.x) >> 6;
  int lane = threadIdx.x & 63;
  if (wid >= NROWS) return;
  int b = wid / ROWS_PER_B;
  int r = wid - b * ROWS_PER_B;
  int z = r / PADW;
  int y = r - z * PADW;
  bool padrow = (z < PAD || z >= PAD + NV || y < PAD || y >= PAD + NV);
  const float TH = 0.84729786f;  // ln(0.7/0.3): sigmoid(l)>0.7 <=> l>TH
  u64* rowp = X + (size_t)b * WPB + (z * PADW + y) * WPR;
#pragma unroll
  for (int j = 0; j < WPR; ++j) {
    int x = j * 64 + lane;
    bool pred = false;
    if (x < PADW) {
      if (padrow || x < PAD || x >= PAD + NV) {
        pred = true;  // pad voxel = 1
      } else {
        float l = logit[(((size_t)b * NV + (z - PAD)) * NV + (y - PAD)) * NV + (x - PAD)];
        pred = l > TH;
      }
    }
    u64 w = __ballot(pred);
    if (lane == 0) rowp[j] = w;
  }
}

// ---------------------------------------------------------------- fused init, thread/WORD:
// E1 = ero6(X); sk = X & ~dil26(E1); E2 = ero6(E1)   — E1 recomputed in-register
__global__ __launch_bounds__(256) void initf_k(const u64* __restrict__ X,
                                               u64* __restrict__ E1out,
                                               u64* __restrict__ E2out,
                                               u64* __restrict__ skout) {
  int idx = blockIdx.x * blockDim.x + threadIdx.x;
  if (idx >= NWORDS) return;
  int b, z, y, j;
  decompW(idx, b, z, y, j);
  const u64* Xb = X + (size_t)b * WPB;
  u64 dil = 0;
  u64 c30 = 0, c31 = 0, c32 = 0;  // E1 center row (full)
  u64 ecross = ~0ULL;             // AND of E1 word j over the 4 cross rows
#pragma unroll
  for (int dz = -1; dz <= 1; ++dz) {
#pragma unroll
    for (int dy = -1; dy <= 1; ++dy) {
      int zz = z + dz, yy = y + dy;
      if (!inR(zz) || !inR(yy)) continue;  // dil OR-identity / ero AND-identity
      u64 er[3];
      eroRowFull(Xb, zz, yy, er);
      dil |= hdilj(er[0], er[1], er[2], j);
      if (dz == 0 && dy == 0) { c30 = er[0]; c31 = er[1]; c32 = er[2]; }
      else if (dz * dz + dy * dy == 1) ecross &= selj(er[0], er[1], er[2], j);
    }
  }
  // E2 = horizontal erosion of E1 center row at word j, AND cross rows
  u64 wm = (j == 0) ? 0ULL : ((j == 1) ? c30 : c31);
  u64 wc = selj(c30, c31, c32, j);
  u64 wp = (j == 2) ? 0ULL : ((j == 0) ? c31 : c32);
  u64 lin = (j == 0) ? 1ULL : (wm >> 63);
  u64 rin = (j == 2) ? (1ULL << 5) : (wp << 63);
  u64 e2 = wc & ((wc << 1) | lin) & ((wc >> 1) | rin);
  e2 &= ecross;

  E1out[idx] = wc;
  E2out[idx] = e2;
  skout[idx] = Xb[(z * PADW + y) * WPR + j] & ~dil;  // clean X kills dil junk bits
}

// ---------------------------------------------------------------- fused iteration, thread/WORD:
// delta = E1 & ~dil26(E2); sk2 = delta | sk | (X & dil26(sk)); E3 = ero6(E2)
__global__ __launch_bounds__(256) void upd_k(const u64* __restrict__ X,
                                             const u64* __restrict__ E1,
                                             const u64* __restrict__ E2,
                                             const u64* __restrict__ sk,
                                             u64* __restrict__ sk2,
                                             u64* __restrict__ E3) {
  int idx = blockIdx.x * blockDim.x + threadIdx.x;
  if (idx >= NWORDS) return;
  int b, z, y, j;
  decompW(idx, b, z, y, j);
  size_t boff = (size_t)b * WPB;
  const u64* Eb = E2 + boff;
  const u64* Sb = sk + boff;
  u64 acc = 0, dsk = 0;
  u64 cc3[3], skcw = 0;
  u64 ecross = ~0ULL;
#pragma unroll
  for (int dz = -1; dz <= 1; ++dz) {
#pragma unroll
    for (int dy = -1; dy <= 1; ++dy) {
      int zz = z + dz, yy = y + dy;
      if (!inR(zz) || !inR(yy)) continue;
      u64 t3[3], s3[3];
      load3w(Eb, zz, yy, j, t3);
      load3w(Sb, zz, yy, j, s3);
      acc |= hdilw(t3);
      dsk |= hdilw(s3);
      if (dz == 0 && dy == 0) {
        cc3[0] = t3[0]; cc3[1] = t3[1]; cc3[2] = t3[2];
        skcw = s3[1];
      } else if (dz * dz + dy * dy == 1) {
        ecross &= t3[1];
      }
    }
  }
  u64 e = herow(cc3, j) & ecross;
  u64 delta = E1[idx] & ~acc;
  u64 s1 = (X[idx] & dsk) | skcw;
  sk2[idx] = delta | s1;
  E3[idx] = e;
}

// ---------------------------------------------------------------- reduction stage 1 (no atomics)
__global__ __launch_bounds__(256) void reduce1_k(const float* __restrict__ logit,
                                                 const float* __restrict__ vcl,
                                                 const u64* __restrict__ S,
                                                 float* __restrict__ partials) {
  int tid = blockIdx.x * 256 + threadIdx.x;
  float p[8];
#pragma unroll
  for (int k = 0; k < 8; ++k) p[k] = 0.f;
  for (int s = tid; s < NV3 / 4; s += RBLK * 256) {
    int i = s << 2;
    int z = i >> 14, y = (i >> 7) & 127, x = i & 127;
#pragma unroll
    for (int b = 0; b < NBATCH; ++b) {
      float4 lv = ((const float4*)(logit + (size_t)b * NV3))[s];
      float4 cv = ((const float4*)(vcl + (size_t)b * NV3))[s];
      const u64* rowp = S + (size_t)b * WPB + ((size_t)(z + PAD) * PADW + (y + PAD)) * WPR;
      float lf[4] = {lv.x, lv.y, lv.z, lv.w};
      float cf[4] = {cv.x, cv.y, cv.z, cv.w};
#pragma unroll
      for (int k = 0; k < 4; ++k) {
        float vp = 1.0f / (1.0f + expf(-lf[k]));
        int xp = x + k + PAD;
        u64 w = rowp[xp >> 6];
        float sv = (float)((w >> (xp & 63)) & 1ULL);
        float c = cf[k];
        p[b * 4 + 0] += vp * c;
        p[b * 4 + 1] += c;
        p[b * 4 + 2] += c * vp * sv;
        p[b * 4 + 3] += vp * sv;
      }
    }
  }
#pragma unroll
  for (int k = 0; k < 8; ++k)
    for (int off = 32; off > 0; off >>= 1) p[k] += __shfl_down(p[k], off);
  __shared__ float ls[4][8];
  int wid = threadIdx.x >> 6, lane = threadIdx.x & 63;
  if (lane == 0) {
#pragma unroll
    for (int k = 0; k < 8; ++k) ls[wid][k] = p[k];
  }
  __syncthreads();
  if (threadIdx.x == 0) {
#pragma unroll
    for (int k = 0; k < 8; ++k)
      partials[k * RBLK + blockIdx.x] = ls[0][k] + ls[1][k] + ls[2][k] + ls[3][k];
  }
}

// ---------------------------------------------------------------- reduction stage 2 + loss
__global__ void finalize2_k(const float* __restrict__ partials, float* __restrict__ out) {
  int t = threadIdx.x;  // 512 threads
  double s[8];
#pragma unroll
  for (int k = 0; k < 8; ++k) s[k] = (double)partials[k * RBLK + t];
#pragma unroll
  for (int k = 0; k < 8; ++k)
    for (int off = 32; off > 0; off >>= 1) s[k] += __shfl_down(s[k], off);
  __shared__ double ls[8][8];
  int wid = t >> 6, lane = t & 63;
  if (lane == 0) {
#pragma unroll
    for (int k = 0; k < 8; ++k) ls[k][wid] = s[k];
  }
  __syncthreads();
  if (t == 0) {
    double a[8];
#pragma unroll
    for (int k = 0; k < 8; ++k) {
      a[k] = 0.0;
      for (int w = 0; w < 8; ++w) a[k] += ls[k][w];
    }
    const double eps = 1e-12;
    double tp = 0.5 * ((a[0] + eps) / (a[1] + eps) + (a[4] + eps) / (a[5] + eps));
    double ts = 0.5 * ((a[2] + eps) / (a[3] + eps) + (a[6] + eps) / (a[7] + eps));
    out[0] = (float)(1.0 - (2.0 * tp * ts + eps) / (tp + ts + eps));
  }
}

// ---------------------------------------------------------------- host side
extern "C" void kernel_launch(void* const* d_in, const int* in_sizes, int n_in,
                              void* d_out, int out_size, void* d_ws, size_t ws_size,
                              hipStream_t stream) {
  const float* logit = (const float*)d_in[0];  // Vlogit
  const float* vcl = (const float*)d_in[1];    // Vcl
  // d_in[2] (Vedt) unused by the reference loss
  float* out = (float*)d_out;

  const size_t bufW = (size_t)NWORDS;
  u64* base = (u64*)d_ws;
  u64* B[6];
  for (int i = 0; i < 6; ++i) B[i] = base + (size_t)i * bufW;
  float* partials = (float*)(base + 6 * bufW);  // 8*RBLK floats = 16 KB

  const int mThreads = 256;
  const int mBlocks = (NWORDS + mThreads - 1) / mThreads;  // 421
  const int bBlocks = (NROWS + 3) / 4;                     // binpack: 4 waves/block

  binpack_k<<<bBlocks, 256, 0, stream>>>(logit, B[0]);

  // ---- skeletonize #1 (5 iters)
  u64 *X = B[0], *E1 = B[1], *E2 = B[2], *E3 = B[3], *sk = B[4], *sk2 = B[5];
  initf_k<<<mBlocks, mThreads, 0, stream>>>(X, E1, E2, sk);
  for (int it = 0; it < 5; ++it) {
    upd_k<<<mBlocks, mThreads, 0, stream>>>(X, E1, E2, sk, sk2, E3);
    u64* t = X; X = E1; E1 = E2; E2 = E3; E3 = t;
    t = sk; sk = sk2; sk2 = t;
  }
  u64* S1 = sk;  // binary support == clamped skel

  // ---- skeletonize #2 (2 iters) on S1, reusing the retired buffers
  u64 *X2 = S1, *E1b = X, *E2b = E1, *E3b = E2, *skb = E3, *sk2b = sk2;
  initf_k<<<mBlocks, mThreads, 0, stream>>>(X2, E1b, E2b, skb);
  for (int it = 0; it < 2; ++it) {
    upd_k<<<mBlocks, mThreads, 0, stream>>>(X2, E1b, E2b, skb, sk2b, E3b);
    u64* t = X2; X2 = E1b; E1b = E2b; E2b = E3b; E3b = t;
    t = skb; skb = sk2b; sk2b = t;
  }
  u64* Sfinal = skb;

  reduce1_k<<<RBLK, 256, 0, stream>>>(logit, vcl, Sfinal, partials);
  finalize2_k<<<1, 512, 0, stream>>>(partials, out);
}